// Round 2
// baseline (171.868 us; speedup 1.0000x reference)
//
#include <hip/hip_runtime.h>

typedef __attribute__((ext_vector_type(8))) short bf16x8;
typedef __attribute__((ext_vector_type(4))) float f32x4;

#define WIDTH  2048
#define NHEADS 16
#define HDIM   128
#define BM     64

__device__ __forceinline__ unsigned short f2bf(float f) {
  union { float f; unsigned int u; } v; v.f = f;
  unsigned int u = v.u;
  unsigned int r = (u + 0x7FFFu + ((u >> 16) & 1u)) >> 16;  // RNE
  return (unsigned short)r;
}

// Prep: transpose w_in/w_a [h][i][j] -> bf16 [h][j][i]; precompute 8*softplus(a_param).
__global__ __launch_bounds__(256) void prep_kernel(
    const float* __restrict__ w_in, const float* __restrict__ w_a,
    const float* __restrict__ a_param,
    unsigned short* __restrict__ wTin, unsigned short* __restrict__ wTa,
    float* __restrict__ sp8) {
  int tid = blockIdx.x * 256 + threadIdx.x;    // 0 .. 16*128*128-1
  int h   = tid >> 14;
  int rem = tid & 16383;
  int j   = rem >> 7;
  int i   = rem & 127;
  int src = (h << 14) + (i << 7) + j;
  wTin[tid] = f2bf(w_in[src]);
  wTa[tid]  = f2bf(w_a[src]);
  if (tid < WIDTH) {
    float v  = a_param[tid];
    float sp = (v > 20.0f) ? v : log1pf(__expf(v));
    sp8[tid] = 8.0f * sp;
  }
}

// Main: block = 64 batch rows x 1 head. Wave w owns output cols [w*32, w*32+32).
// Swapped-operand MFMA: D = W^T * X^T, so D col (lane&15) = batch row,
// D row (l4*4+reg) = output col -> 4 CONSECUTIVE output cols per lane
// -> fully float4-vectorized epilogue.
__global__ __launch_bounds__(256) void rglru_kernel(
    const float* __restrict__ x, const float* __restrict__ state,
    const float* __restrict__ b_in, const float* __restrict__ b_a,
    const unsigned short* __restrict__ wTin, const unsigned short* __restrict__ wTa,
    const float* __restrict__ sp8, float* __restrict__ out) {
  __shared__ unsigned short xs[BM * HDIM];  // bf16 x-tile, XOR-swizzled

  const int bid  = blockIdx.x;
  const int h    = bid & (NHEADS - 1);
  const int rb   = bid >> 4;
  const int t    = threadIdx.x;
  const int lane = t & 63;
  const int wid  = t >> 6;
  const int l15  = lane & 15;
  const int l4   = lane >> 4;

  // ---- stage x tile (BM x HDIM f32 -> bf16 LDS, swizzled) ----
  const float* xtile = x + (long)rb * BM * WIDTH + h * HDIM;
#pragma unroll
  for (int it = 0; it < 8; ++it) {
    int idx = it * 256 + t;            // float4 index within tile (0..2047)
    int r   = idx >> 5;                // row 0..63
    int c4  = idx & 31;                // float4 within row
    float4 v = *(reinterpret_cast<const float4*>(xtile + (long)r * WIDTH) + c4);
    uint2 p;
    p.x = (unsigned int)f2bf(v.x) | ((unsigned int)f2bf(v.y) << 16);
    p.y = (unsigned int)f2bf(v.z) | ((unsigned int)f2bf(v.w) << 16);
    int off = (r * 256 + c4 * 8) ^ ((r & 7) << 4);
    *reinterpret_cast<uint2*>(reinterpret_cast<char*>(xs) + off) = p;
  }
  __syncthreads();

  // ---- MFMA: acc[m][n] = (W^T X^T) block; m = batch-row frag, n = col frag ----
  f32x4 acc_in[4][2], acc_a[4][2];
#pragma unroll
  for (int m = 0; m < 4; ++m)
#pragma unroll
    for (int n = 0; n < 2; ++n) {
      acc_in[m][n] = (f32x4)(0.0f);
      acc_a[m][n]  = (f32x4)(0.0f);
    }

  const unsigned short* wbin = wTin + ((h * HDIM + wid * 32) * HDIM);
  const unsigned short* wba  = wTa  + ((h * HDIM + wid * 32) * HDIM);

#pragma unroll
  for (int kk = 0; kk < 4; ++kk) {
    bf16x8 xfr[4];   // B operand: B[k][i] = x[i][k]; lane: i=l15(+m*16), k=kk*32+l4*8..+8
#pragma unroll
    for (int m = 0; m < 4; ++m) {
      int row  = m * 16 + l15;
      int boff = (row * 256 + kk * 64 + l4 * 16) ^ ((row & 7) << 4);
      xfr[m] = *reinterpret_cast<const bf16x8*>(
          reinterpret_cast<const char*>(xs) + boff);
    }
    bf16x8 win[2], wa[2];  // A operand: A[j][k] = wT[j][k]; lane: j=l15(+n*16), k=kk*32+l4*8
#pragma unroll
    for (int n = 0; n < 2; ++n) {
      int widx = (n * 16 + l15) * HDIM + kk * 32 + l4 * 8;
      win[n] = *reinterpret_cast<const bf16x8*>(wbin + widx);
      wa[n]  = *reinterpret_cast<const bf16x8*>(wba + widx);
    }
#pragma unroll
    for (int m = 0; m < 4; ++m)
#pragma unroll
      for (int n = 0; n < 2; ++n) {
        acc_in[m][n] = __builtin_amdgcn_mfma_f32_16x16x32_bf16(
            win[n], xfr[m], acc_in[m][n], 0, 0, 0);
        acc_a[m][n] = __builtin_amdgcn_mfma_f32_16x16x32_bf16(
            wa[n], xfr[m], acc_a[m][n], 0, 0, 0);
      }
  }

  // ---- epilogue: D layout: batch row = lane&15 (+m*16), out col = l4*4+reg (+n*16) ----
#pragma unroll
  for (int n = 0; n < 2; ++n) {
    int colh0 = wid * 32 + n * 16 + l4 * 4;     // col within head, 4-consecutive
    int col0  = h * HDIM + colh0;               // col within width
    float4 bi  = *reinterpret_cast<const float4*>(b_in + h * HDIM + colh0);
    float4 bav = *reinterpret_cast<const float4*>(b_a  + h * HDIM + colh0);
    float4 sp  = *reinterpret_cast<const float4*>(sp8 + col0);
#pragma unroll
    for (int m = 0; m < 4; ++m) {
      int row = rb * BM + m * 16 + l15;
      long off = (long)row * WIDTH + col0;
      float4 xv = *reinterpret_cast<const float4*>(x + off);
      float4 sv = *reinterpret_cast<const float4*>(state + off);
      float4 o;
      {
        float yin = acc_in[m][n][0] + bi.x;
        float ya  = acc_a[m][n][0] + bav.x;
        float gx = __builtin_amdgcn_rcpf(1.0f + __expf(-yin));
        float ga = __builtin_amdgcn_rcpf(1.0f + __expf(-ya));
        float av = __expf(-ga * sp.x);
        float sc = sqrtf(fmaxf(1.0f - av * av, 0.0f));
        o.x = av * sv.x + gx * xv.x * sc;
      }
      {
        float yin = acc_in[m][n][1] + bi.y;
        float ya  = acc_a[m][n][1] + bav.y;
        float gx = __builtin_amdgcn_rcpf(1.0f + __expf(-yin));
        float ga = __builtin_amdgcn_rcpf(1.0f + __expf(-ya));
        float av = __expf(-ga * sp.y);
        float sc = sqrtf(fmaxf(1.0f - av * av, 0.0f));
        o.y = av * sv.y + gx * xv.y * sc;
      }
      {
        float yin = acc_in[m][n][2] + bi.z;
        float ya  = acc_a[m][n][2] + bav.z;
        float gx = __builtin_amdgcn_rcpf(1.0f + __expf(-yin));
        float ga = __builtin_amdgcn_rcpf(1.0f + __expf(-ya));
        float av = __expf(-ga * sp.z);
        float sc = sqrtf(fmaxf(1.0f - av * av, 0.0f));
        o.z = av * sv.z + gx * xv.z * sc;
      }
      {
        float yin = acc_in[m][n][3] + bi.w;
        float ya  = acc_a[m][n][3] + bav.w;
        float gx = __builtin_amdgcn_rcpf(1.0f + __expf(-yin));
        float ga = __builtin_amdgcn_rcpf(1.0f + __expf(-ya));
        float av = __expf(-ga * sp.w);
        float sc = sqrtf(fmaxf(1.0f - av * av, 0.0f));
        o.w = av * sv.w + gx * xv.w * sc;
      }
      *reinterpret_cast<float4*>(out + off) = o;
    }
  }
}

extern "C" void kernel_launch(void* const* d_in, const int* in_sizes, int n_in,
                              void* d_out, int out_size, void* d_ws, size_t ws_size,
                              hipStream_t stream) {
  const float* x       = (const float*)d_in[0];
  const float* state   = (const float*)d_in[1];
  const float* w_in    = (const float*)d_in[2];
  const float* b_in    = (const float*)d_in[3];
  const float* w_a     = (const float*)d_in[4];
  const float* b_a     = (const float*)d_in[5];
  const float* a_param = (const float*)d_in[6];
  float* out = (float*)d_out;

  unsigned short* wTin = (unsigned short*)d_ws;
  unsigned short* wTa  = wTin + NHEADS * HDIM * HDIM;
  float*          sp8  = (float*)(wTa + NHEADS * HDIM * HDIM);

  // prep: 16*128*128 = 262144 elements -> 1024 blocks
  hipLaunchKernelGGL(prep_kernel, dim3(1024), dim3(256), 0, stream,
                     w_in, w_a, a_param, wTin, wTa, sp8);

  // main: (16384/64) row-blocks * 16 heads = 4096 blocks
  hipLaunchKernelGGL(rglru_kernel, dim3(4096), dim3(256), 0, stream,
                     x, state, b_in, b_a, wTin, wTa, sp8, out);
}

// Round 4
// 119.464 us; speedup vs baseline: 1.4387x; 1.4387x over previous
//
#include <hip/hip_runtime.h>

typedef __attribute__((ext_vector_type(8))) short bf16x8;
typedef __attribute__((ext_vector_type(4))) float f32x4;
typedef __attribute__((ext_vector_type(4))) unsigned short u16x4;

#define WIDTH  2048
#define NHEADS 16
#define HDIM   128
#define BM     64

__device__ __forceinline__ unsigned short f2bf(float f) {
  union { float f; unsigned int u; } v; v.f = f;
  unsigned int u = v.u;
  unsigned int r = (u + 0x7FFFu + ((u >> 16) & 1u)) >> 16;  // RNE
  return (unsigned short)r;
}

__device__ __forceinline__ float bf2f(unsigned short s) {
  union { unsigned int u; float f; } v;
  v.u = ((unsigned int)s) << 16;
  return v.f;
}

// Prep: transpose w_in/w_a [h][i][j] -> bf16 [h][j][i]; precompute 8*softplus(a_param).
__global__ __launch_bounds__(256) void prep_kernel(
    const float* __restrict__ w_in, const float* __restrict__ w_a,
    const float* __restrict__ a_param,
    unsigned short* __restrict__ wTin, unsigned short* __restrict__ wTa,
    float* __restrict__ sp8) {
  int tid = blockIdx.x * 256 + threadIdx.x;    // 0 .. 16*128*128-1
  int h   = tid >> 14;
  int rem = tid & 16383;
  int j   = rem >> 7;
  int i   = rem & 127;
  int src = (h << 14) + (i << 7) + j;
  wTin[tid] = f2bf(w_in[src]);
  wTa[tid]  = f2bf(w_a[src]);
  if (tid < WIDTH) {
    float v  = a_param[tid];
    float sp = (v > 20.0f) ? v : log1pf(__expf(v));
    sp8[tid] = 8.0f * sp;
  }
}

// Main: block = 64 batch rows x 1 head. Wave w owns output cols [w*32, w*32+32).
// Swapped-operand MFMA: D col (lane&15) = batch row, D row (l4*4+reg) = out col.
// Epilogue x comes from the bf16 LDS tile (no global re-read); state is
// prefetched into registers before the MFMA loop (latency hidden).
__global__ __launch_bounds__(256, 3) void rglru_kernel(
    const float* __restrict__ x, const float* __restrict__ state,
    const float* __restrict__ b_in, const float* __restrict__ b_a,
    const unsigned short* __restrict__ wTin, const unsigned short* __restrict__ wTa,
    const float* __restrict__ sp8, float* __restrict__ out) {
  __shared__ unsigned short xs[BM * HDIM];  // bf16 x-tile, XOR-swizzled

  const int bid  = blockIdx.x;
  const int h    = bid & (NHEADS - 1);
  const int rb   = bid >> 4;
  const int t    = threadIdx.x;
  const int lane = t & 63;
  const int wid  = t >> 6;
  const int l15  = lane & 15;
  const int l4   = lane >> 4;

  // ---- stage x tile (BM x HDIM f32 -> bf16 LDS, swizzled) ----
  const float* xtile = x + (long)rb * BM * WIDTH + h * HDIM;
#pragma unroll
  for (int it = 0; it < 8; ++it) {
    int idx = it * 256 + t;            // float4 index within tile (0..2047)
    int r   = idx >> 5;                // row 0..63
    int c4  = idx & 31;                // float4 within row
    f32x4 v = __builtin_nontemporal_load(
        reinterpret_cast<const f32x4*>(xtile + (long)r * WIDTH) + c4);
    uint2 p;
    p.x = (unsigned int)f2bf(v.x) | ((unsigned int)f2bf(v.y) << 16);
    p.y = (unsigned int)f2bf(v.z) | ((unsigned int)f2bf(v.w) << 16);
    int off = (r * 256 + c4 * 8) ^ ((r & 7) << 4);
    *reinterpret_cast<uint2*>(reinterpret_cast<char*>(xs) + off) = p;
  }
  __syncthreads();

  // ---- prefetch state + per-column constants (overlaps with MFMA phase) ----
  f32x4 sreg[2][4];
  f32x4 bi4[2], ba4[2], sp4[2];
#pragma unroll
  for (int n = 0; n < 2; ++n) {
    int colh0 = wid * 32 + n * 16 + l4 * 4;
    int col0  = h * HDIM + colh0;
#pragma unroll
    for (int m = 0; m < 4; ++m) {
      long row = (long)(rb * BM + m * 16 + l15);
      sreg[n][m] = __builtin_nontemporal_load(
          reinterpret_cast<const f32x4*>(state + row * WIDTH + col0));
    }
    bi4[n] = *reinterpret_cast<const f32x4*>(b_in + h * HDIM + colh0);
    ba4[n] = *reinterpret_cast<const f32x4*>(b_a + h * HDIM + colh0);
    sp4[n] = *reinterpret_cast<const f32x4*>(sp8 + col0);
  }

  // ---- MFMA: acc[m][n]; m = batch-row frag, n = col frag ----
  f32x4 acc_in[4][2], acc_a[4][2];
#pragma unroll
  for (int m = 0; m < 4; ++m)
#pragma unroll
    for (int n = 0; n < 2; ++n) {
      acc_in[m][n] = (f32x4)(0.0f);
      acc_a[m][n]  = (f32x4)(0.0f);
    }

  const unsigned short* wbin = wTin + ((h * HDIM + wid * 32) * HDIM);
  const unsigned short* wba  = wTa  + ((h * HDIM + wid * 32) * HDIM);

#pragma unroll
  for (int kk = 0; kk < 4; ++kk) {
    bf16x8 xfr[4];   // B operand: x[i][k]; lane: i = m*16+l15, k = kk*32 + l4*8 ..
#pragma unroll
    for (int m = 0; m < 4; ++m) {
      int row  = m * 16 + l15;
      int boff = (row * 256 + kk * 64 + l4 * 16) ^ ((row & 7) << 4);
      xfr[m] = *reinterpret_cast<const bf16x8*>(
          reinterpret_cast<const char*>(xs) + boff);
    }
    bf16x8 win[2], wa[2];  // A operand: wT[j][k]; lane: j = n*16+l15
#pragma unroll
    for (int n = 0; n < 2; ++n) {
      int widx = (n * 16 + l15) * HDIM + kk * 32 + l4 * 8;
      win[n] = *reinterpret_cast<const bf16x8*>(wbin + widx);
      wa[n]  = *reinterpret_cast<const bf16x8*>(wba + widx);
    }
#pragma unroll
    for (int m = 0; m < 4; ++m)
#pragma unroll
      for (int n = 0; n < 2; ++n) {
        acc_in[m][n] = __builtin_amdgcn_mfma_f32_16x16x32_bf16(
            win[n], xfr[m], acc_in[m][n], 0, 0, 0);
        acc_a[m][n] = __builtin_amdgcn_mfma_f32_16x16x32_bf16(
            wa[n], xfr[m], acc_a[m][n], 0, 0, 0);
      }
  }

  // ---- epilogue: row = m*16+l15 (batch), cols = colh0..+3 (consecutive) ----
#pragma unroll
  for (int n = 0; n < 2; ++n) {
    int colh0 = wid * 32 + n * 16 + l4 * 4;
    int col0  = h * HDIM + colh0;
    f32x4 bi = bi4[n], bav = ba4[n], sp = sp4[n];
#pragma unroll
    for (int m = 0; m < 4; ++m) {
      int lrow = m * 16 + l15;
      long off = (long)(rb * BM + lrow) * WIDTH + col0;
      // x (bf16) from LDS — same tile staged for MFMA
      int xoff = (lrow * 256 + colh0 * 2) ^ ((lrow & 7) << 4);
      u16x4 xb = *reinterpret_cast<const u16x4*>(
          reinterpret_cast<const char*>(xs) + xoff);
      f32x4 sv = sreg[n][m];
      f32x4 o;
#pragma unroll
      for (int r = 0; r < 4; ++r) {
        float yin = acc_in[m][n][r] + bi[r];
        float ya  = acc_a[m][n][r] + bav[r];
        float gx = __builtin_amdgcn_rcpf(1.0f + __expf(-yin));
        float ga = __builtin_amdgcn_rcpf(1.0f + __expf(-ya));
        float av = __expf(-ga * sp[r]);
        float sc = sqrtf(fmaxf(1.0f - av * av, 0.0f));
        o[r] = av * sv[r] + gx * bf2f(xb[r]) * sc;
      }
      __builtin_nontemporal_store(o, reinterpret_cast<f32x4*>(out + off));
    }
  }
}

extern "C" void kernel_launch(void* const* d_in, const int* in_sizes, int n_in,
                              void* d_out, int out_size, void* d_ws, size_t ws_size,
                              hipStream_t stream) {
  const float* x       = (const float*)d_in[0];
  const float* state   = (const float*)d_in[1];
  const float* w_in    = (const float*)d_in[2];
  const float* b_in    = (const float*)d_in[3];
  const float* w_a     = (const float*)d_in[4];
  const float* b_a     = (const float*)d_in[5];
  const float* a_param = (const float*)d_in[6];
  float* out = (float*)d_out;

  unsigned short* wTin = (unsigned short*)d_ws;
  unsigned short* wTa  = wTin + NHEADS * HDIM * HDIM;
  float*          sp8  = (float*)(wTa + NHEADS * HDIM * HDIM);

  // prep: 16*128*128 = 262144 elements -> 1024 blocks
  hipLaunchKernelGGL(prep_kernel, dim3(1024), dim3(256), 0, stream,
                     w_in, w_a, a_param, wTin, wTa, sp8);

  // main: (16384/64) row-blocks * 16 heads = 4096 blocks
  hipLaunchKernelGGL(rglru_kernel, dim3(4096), dim3(256), 0, stream,
                     x, state, b_in, b_a, wTin, wTa, sp8, out);
}

// Round 5
// 116.617 us; speedup vs baseline: 1.4738x; 1.0244x over previous
//
#include <hip/hip_runtime.h>

typedef __attribute__((ext_vector_type(8))) short bf16x8;
typedef __attribute__((ext_vector_type(4))) float f32x4;
typedef __attribute__((ext_vector_type(4))) unsigned short u16x4;

#define WIDTH  2048
#define NHEADS 16
#define HDIM   128
#define BM     64

__device__ __forceinline__ unsigned short f2bf(float f) {
  union { float f; unsigned int u; } v; v.f = f;
  unsigned int u = v.u;
  unsigned int r = (u + 0x7FFFu + ((u >> 16) & 1u)) >> 16;  // RNE
  return (unsigned short)r;
}

__device__ __forceinline__ float bf2f(unsigned short s) {
  union { unsigned int u; float f; } v;
  v.u = ((unsigned int)s) << 16;
  return v.f;
}

// Prep: transpose w_in/w_a [h][i][j] -> bf16 [h][j][i]; precompute 8*softplus(a_param).
__global__ __launch_bounds__(256) void prep_kernel(
    const float* __restrict__ w_in, const float* __restrict__ w_a,
    const float* __restrict__ a_param,
    unsigned short* __restrict__ wTin, unsigned short* __restrict__ wTa,
    float* __restrict__ sp8) {
  int tid = blockIdx.x * 256 + threadIdx.x;    // 0 .. 16*128*128-1
  int h   = tid >> 14;
  int rem = tid & 16383;
  int j   = rem >> 7;
  int i   = rem & 127;
  int src = (h << 14) + (i << 7) + j;
  wTin[tid] = f2bf(w_in[src]);
  wTa[tid]  = f2bf(w_a[src]);
  if (tid < WIDTH) {
    float v  = a_param[tid];
    float sp = (v > 20.0f) ? v : log1pf(__expf(v));
    sp8[tid] = 8.0f * sp;
  }
}

// Main: block = 64 batch rows x 1 head. Wave w owns output cols [w*32, w*32+32).
// Swapped-operand MFMA: D col (lane&15) = batch row, D row (l4*4+reg) = out col.
// Epilogue x comes from the bf16 LDS tile (no global re-read). Register budget
// kept under 128 total (incl. 64 acc regs) so 4 blocks/CU stay resident —
// TLP across blocks hides the epilogue state-load latency.
__global__ __launch_bounds__(256, 4) void rglru_kernel(
    const float* __restrict__ x, const float* __restrict__ state,
    const float* __restrict__ b_in, const float* __restrict__ b_a,
    const unsigned short* __restrict__ wTin, const unsigned short* __restrict__ wTa,
    const float* __restrict__ sp8, float* __restrict__ out) {
  __shared__ unsigned short xs[BM * HDIM];  // bf16 x-tile, XOR-swizzled

  const int bid  = blockIdx.x;
  const int h    = bid & (NHEADS - 1);
  const int rb   = bid >> 4;
  const int t    = threadIdx.x;
  const int lane = t & 63;
  const int wid  = t >> 6;
  const int l15  = lane & 15;
  const int l4   = lane >> 4;

  // ---- stage x tile (BM x HDIM f32 -> bf16 LDS, swizzled) ----
  const float* xtile = x + (long)rb * BM * WIDTH + h * HDIM;
#pragma unroll
  for (int it = 0; it < 8; ++it) {
    int idx = it * 256 + t;            // float4 index within tile (0..2047)
    int r   = idx >> 5;                // row 0..63
    int c4  = idx & 31;                // float4 within row
    f32x4 v = __builtin_nontemporal_load(
        reinterpret_cast<const f32x4*>(xtile + (long)r * WIDTH) + c4);
    uint2 p;
    p.x = (unsigned int)f2bf(v.x) | ((unsigned int)f2bf(v.y) << 16);
    p.y = (unsigned int)f2bf(v.z) | ((unsigned int)f2bf(v.w) << 16);
    int off = (r * 256 + c4 * 8) ^ ((r & 7) << 4);
    *reinterpret_cast<uint2*>(reinterpret_cast<char*>(xs) + off) = p;
  }
  __syncthreads();

  // ---- MFMA: acc[m][n]; m = batch-row frag, n = col frag ----
  f32x4 acc_in[4][2], acc_a[4][2];
#pragma unroll
  for (int m = 0; m < 4; ++m)
#pragma unroll
    for (int n = 0; n < 2; ++n) {
      acc_in[m][n] = (f32x4)(0.0f);
      acc_a[m][n]  = (f32x4)(0.0f);
    }

  const unsigned short* wbin = wTin + ((h * HDIM + wid * 32) * HDIM);
  const unsigned short* wba  = wTa  + ((h * HDIM + wid * 32) * HDIM);

#pragma unroll
  for (int kk = 0; kk < 4; ++kk) {
    bf16x8 xfr[4];   // B operand: x[i][k]; lane: i = m*16+l15, k = kk*32 + l4*8 ..
#pragma unroll
    for (int m = 0; m < 4; ++m) {
      int row  = m * 16 + l15;
      int boff = (row * 256 + kk * 64 + l4 * 16) ^ ((row & 7) << 4);
      xfr[m] = *reinterpret_cast<const bf16x8*>(
          reinterpret_cast<const char*>(xs) + boff);
    }
    bf16x8 win[2], wa[2];  // A operand: wT[j][k]; lane: j = n*16+l15
#pragma unroll
    for (int n = 0; n < 2; ++n) {
      int widx = (n * 16 + l15) * HDIM + kk * 32 + l4 * 8;
      win[n] = *reinterpret_cast<const bf16x8*>(wbin + widx);
      wa[n]  = *reinterpret_cast<const bf16x8*>(wba + widx);
    }
#pragma unroll
    for (int m = 0; m < 4; ++m)
#pragma unroll
      for (int n = 0; n < 2; ++n) {
        acc_in[m][n] = __builtin_amdgcn_mfma_f32_16x16x32_bf16(
            win[n], xfr[m], acc_in[m][n], 0, 0, 0);
        acc_a[m][n] = __builtin_amdgcn_mfma_f32_16x16x32_bf16(
            wa[n], xfr[m], acc_a[m][n], 0, 0, 0);
      }
  }

  // ---- epilogue: row = m*16+l15 (batch), cols = colh0..+3 (consecutive) ----
#pragma unroll
  for (int n = 0; n < 2; ++n) {
    int colh0 = wid * 32 + n * 16 + l4 * 4;
    int col0  = h * HDIM + colh0;
    f32x4 bi  = *reinterpret_cast<const f32x4*>(b_in + h * HDIM + colh0);
    f32x4 bav = *reinterpret_cast<const f32x4*>(b_a + h * HDIM + colh0);
    f32x4 sp  = *reinterpret_cast<const f32x4*>(sp8 + col0);
#pragma unroll
    for (int m = 0; m < 4; ++m) {
      int lrow = m * 16 + l15;
      long off = (long)(rb * BM + lrow) * WIDTH + col0;
      // x (bf16) from LDS — same tile staged for MFMA
      int xoff = (lrow * 256 + colh0 * 2) ^ ((lrow & 7) << 4);
      u16x4 xb = *reinterpret_cast<const u16x4*>(
          reinterpret_cast<const char*>(xs) + xoff);
      f32x4 sv = __builtin_nontemporal_load(
          reinterpret_cast<const f32x4*>(state + off));
      f32x4 o;
#pragma unroll
      for (int r = 0; r < 4; ++r) {
        float yin = acc_in[m][n][r] + bi[r];
        float ya  = acc_a[m][n][r] + bav[r];
        float gx = __builtin_amdgcn_rcpf(1.0f + __expf(-yin));
        float ga = __builtin_amdgcn_rcpf(1.0f + __expf(-ya));
        float av = __expf(-ga * sp[r]);
        float sc = sqrtf(fmaxf(1.0f - av * av, 0.0f));
        o[r] = av * sv[r] + gx * bf2f(xb[r]) * sc;
      }
      *reinterpret_cast<f32x4*>(out + off) = o;
    }
  }
}

extern "C" void kernel_launch(void* const* d_in, const int* in_sizes, int n_in,
                              void* d_out, int out_size, void* d_ws, size_t ws_size,
                              hipStream_t stream) {
  const float* x       = (const float*)d_in[0];
  const float* state   = (const float*)d_in[1];
  const float* w_in    = (const float*)d_in[2];
  const float* b_in    = (const float*)d_in[3];
  const float* w_a     = (const float*)d_in[4];
  const float* b_a     = (const float*)d_in[5];
  const float* a_param = (const float*)d_in[6];
  float* out = (float*)d_out;

  unsigned short* wTin = (unsigned short*)d_ws;
  unsigned short* wTa  = wTin + NHEADS * HDIM * HDIM;
  float*          sp8  = (float*)(wTa + NHEADS * HDIM * HDIM);

  // prep: 16*128*128 = 262144 elements -> 1024 blocks
  hipLaunchKernelGGL(prep_kernel, dim3(1024), dim3(256), 0, stream,
                     w_in, w_a, a_param, wTin, wTa, sp8);

  // main: (16384/64) row-blocks * 16 heads = 4096 blocks
  hipLaunchKernelGGL(rglru_kernel, dim3(4096), dim3(256), 0, stream,
                     x, state, b_in, b_a, wTin, wTa, sp8, out);
}